// Round 10
// baseline (670.843 us; speedup 1.0000x reference)
//
#include <hip/hip_runtime.h>
#include <math.h>

#define HIDDEN 30
#define SP 32  // padded row stride (floats) -> 128B rows

// ---------------- degree / norm ----------------

__global__ void k_hist(const int* __restrict__ col, unsigned* __restrict__ deg, int E) {
    int e = blockIdx.x * blockDim.x + threadIdx.x;
    if (e < E) atomicAdd(&deg[col[e]], 1u);
}

__global__ void k_dis(const unsigned* __restrict__ deg, float* __restrict__ dis, int N) {
    int i = blockIdx.x * blockDim.x + threadIdx.x;
    if (i < N) dis[i] = rsqrtf((float)deg[i] + 1.0f);
}

// ---------------- rowptr (scan of deg) ----------------

__global__ void k_scan_block(const unsigned* __restrict__ deg, unsigned* __restrict__ inc,
                             unsigned* __restrict__ bsum, int N) {
    __shared__ unsigned s[1024];
    int i = blockIdx.x * 1024 + threadIdx.x;
    unsigned v = (i < N) ? deg[i] : 0u;
    s[threadIdx.x] = v;
    __syncthreads();
    for (int off = 1; off < 1024; off <<= 1) {
        unsigned t = (threadIdx.x >= off) ? s[threadIdx.x - off] : 0u;
        __syncthreads();
        s[threadIdx.x] += t;
        __syncthreads();
    }
    if (i < N) inc[i] = s[threadIdx.x];
    if (threadIdx.x == 1023) bsum[blockIdx.x] = s[1023];
}

__global__ void k_scan_bsums(unsigned* __restrict__ bsum, int nb) {
    __shared__ unsigned s[128];
    int i = threadIdx.x;
    s[i] = (i < nb) ? bsum[i] : 0u;
    __syncthreads();
    for (int off = 1; off < 128; off <<= 1) {
        unsigned t = (i >= off) ? s[i - off] : 0u;
        __syncthreads();
        s[i] += t;
        __syncthreads();
    }
    if (i < nb) bsum[i] = s[i];
}

__global__ void k_rowptr(const unsigned* __restrict__ bsum, unsigned* __restrict__ rowptr, int N) {
    int i = blockIdx.x * 1024 + threadIdx.x;
    if (i >= N) return;
    int blk = i >> 10;
    if (blk) rowptr[i + 1] += bsum[blk - 1];
    if (i == 0) rowptr[0] = 0u;
}

__global__ void k_cnt_copy(const unsigned* __restrict__ rowptr, unsigned* __restrict__ cnt, int N) {
    int i = blockIdx.x * blockDim.x + threadIdx.x;
    if (i < N) cnt[i] = rowptr[i];
}

// ---------------- bucketed edge sort (kills scatter write-amplification) ----------------

// per-block bucket histogram; blockhist[bucket*nblocks + block]
__global__ void k_bhist(const int* __restrict__ col, unsigned* __restrict__ blockhist,
                        int E, int chunk, int nblocks, int shift, int NB) {
    __shared__ unsigned h[256];
    for (int i = threadIdx.x; i < NB; i += 256) h[i] = 0;
    __syncthreads();
    int s = blockIdx.x * chunk, e = min(E, s + chunk);
    for (int j = s + threadIdx.x; j < e; j += 256) atomicAdd(&h[col[j] >> shift], 1u);
    __syncthreads();
    for (int i = threadIdx.x; i < NB; i += 256)
        blockhist[(size_t)i * nblocks + blockIdx.x] = h[i];
}

// exclusive scan (in place) of blockhist, M = NB*nblocks values; single block
__global__ void k_bscan(unsigned* __restrict__ a, int M) {
    __shared__ unsigned s[1024];
    __shared__ unsigned carry;
    if (threadIdx.x == 0) carry = 0;
    __syncthreads();
    for (int base = 0; base < M; base += 1024) {
        int i = base + threadIdx.x;
        unsigned v = (i < M) ? a[i] : 0u;
        s[threadIdx.x] = v;
        __syncthreads();
        for (int off = 1; off < 1024; off <<= 1) {
            unsigned t = (threadIdx.x >= off) ? s[threadIdx.x - off] : 0u;
            __syncthreads();
            s[threadIdx.x] += t;
            __syncthreads();
        }
        unsigned excl = s[threadIdx.x] - v + carry;
        if (i < M) a[i] = excl;
        __syncthreads();
        if (threadIdx.x == 1023) carry += s[1023];
        __syncthreads();
    }
}

// write (row,col) pairs bucket-major; contiguous runs per (block,bucket)
__global__ void k_bscatter(const int* __restrict__ row, const int* __restrict__ col,
                           const unsigned* __restrict__ bh, int2* __restrict__ pairs,
                           int E, int chunk, int nblocks, int shift, int NB) {
    __shared__ unsigned base[256];
    __shared__ unsigned cnt[256];
    for (int i = threadIdx.x; i < NB; i += 256) {
        base[i] = bh[(size_t)i * nblocks + blockIdx.x];
        cnt[i] = 0;
    }
    __syncthreads();
    int s = blockIdx.x * chunk, e = min(E, s + chunk);
    for (int j = s + threadIdx.x; j < e; j += 256) {
        int c = col[j];
        int k = c >> shift;
        unsigned off = base[k] + atomicAdd(&cnt[k], 1u);
        pairs[off] = make_int2(row[j], c);
    }
}

// final positional scatter; one block per bucket -> writes stay in a ~32KB L2 window
__global__ void k_fscatter(const unsigned* __restrict__ bh, const int2* __restrict__ pairs,
                           unsigned* __restrict__ cnt, int* __restrict__ src,
                           int E, int nblocks, int NB) {
    int k = blockIdx.x;
    unsigned s = bh[(size_t)k * nblocks];
    unsigned e = (k + 1 < NB) ? bh[(size_t)(k + 1) * nblocks] : (unsigned)E;
    for (unsigned j = s + threadIdx.x; j < e; j += blockDim.x) {
        int2 p = pairs[j];
        unsigned q = atomicAdd(&cnt[p.y], 1u);
        src[q] = p.x;
    }
}

// per-graph node ranges from sorted batch
__global__ void k_gstart(const int* __restrict__ batch, int* __restrict__ gstart, int N, int G) {
    int i = blockIdx.x * blockDim.x + threadIdx.x;
    if (i >= N) return;
    int b = batch[i];
    if (i == 0) {
        for (int g = 0; g <= b; ++g) gstart[g] = 0;
    } else {
        int p = batch[i - 1];
        if (p != b) for (int g = p + 1; g <= b; ++g) gstart[g] = i;
    }
    if (i == N - 1) {
        for (int g = b + 1; g <= G; ++g) gstart[g] = N;
    }
}

// ---------------- per-layer kernels ----------------

__global__ void k_transform0(const float* __restrict__ x, const float* __restrict__ W,
                             const float* __restrict__ dis, float* __restrict__ S, int N) {
    __shared__ float Ws[128 * HIDDEN];
    __shared__ float Xs[8 * 128];
    for (int i = threadIdx.x; i < 128 * HIDDEN; i += 256) Ws[i] = W[i];
    int nb = blockIdx.x * 8;
    for (int i = threadIdx.x; i < 8 * 128; i += 256) {
        int nn = nb + (i >> 7);
        Xs[i] = (nn < N) ? x[(size_t)nn * 128 + (i & 127)] : 0.f;
    }
    __syncthreads();
    int nl = threadIdx.x >> 5, h = threadIdx.x & 31;
    int n = nb + nl;
    if (n >= N) return;
    float acc = 0.f;
    if (h < HIDDEN) {
        const float* xr = &Xs[nl * 128];
#pragma unroll 8
        for (int f = 0; f < 128; ++f) acc += xr[f] * Ws[f * HIDDEN + h];
        acc *= dis[n];
    }
    S[(size_t)n * SP + h] = (h < HIDDEN) ? acc : 0.f;
}

__global__ void k_transform_small(const float* __restrict__ in, const float* __restrict__ W,
                                  const float* __restrict__ dis, float* __restrict__ S, int N) {
    __shared__ float Ws[HIDDEN * HIDDEN];
    __shared__ float Bs[8 * SP];
    for (int i = threadIdx.x; i < HIDDEN * HIDDEN; i += 256) Ws[i] = W[i];
    int nb = blockIdx.x * 8;
    {
        int i = threadIdx.x;
        int nn = nb + (i >> 5);
        Bs[i] = (nn < N) ? in[(size_t)nn * SP + (i & 31)] : 0.f;
    }
    __syncthreads();
    int nl = threadIdx.x >> 5, h = threadIdx.x & 31;
    int n = nb + nl;
    if (n >= N) return;
    float acc = 0.f;
    if (h < HIDDEN) {
        const float* r = &Bs[nl * SP];
#pragma unroll
        for (int k = 0; k < HIDDEN; ++k) acc += r[k] * Ws[k * HIDDEN + h];
        acc *= dis[n];
    }
    S[(size_t)n * SP + h] = (h < HIDDEN) ? acc : 0.f;
}

// one wave per node: 8 lane-groups x float4 -> 8 neighbor rows (1KB) in flight/iter
__global__ void k_agg(const unsigned* __restrict__ rowptr, const int* __restrict__ src,
                      const float4* __restrict__ S4, const float* __restrict__ dis,
                      const float* __restrict__ b, float4* __restrict__ B4, int N, int do_relu) {
    int w = threadIdx.x >> 6;
    int lane = threadIdx.x & 63;
    int n = blockIdx.x * 4 + w;
    if (n >= N) return;
    int g = lane >> 3, s = lane & 7;
    float ax = 0.f, ay = 0.f, az = 0.f, aw = 0.f;
    if (g == 0) {  // self-loop term
        float4 v = S4[(size_t)n * 8 + s];
        ax = v.x; ay = v.y; az = v.z; aw = v.w;
    }
    unsigned beg = rowptr[n], end = rowptr[n + 1];
    for (unsigned j = beg + g; j < end; j += 8) {
        int r = src[j];
        float4 v = S4[(size_t)r * 8 + s];
        ax += v.x; ay += v.y; az += v.z; aw += v.w;
    }
    for (int off = 8; off < 64; off <<= 1) {
        ax += __shfl_xor(ax, off);
        ay += __shfl_xor(ay, off);
        az += __shfl_xor(az, off);
        aw += __shfl_xor(aw, off);
    }
    if (g == 0) {
        float d = dis[n];
        int h = s * 4;
        float o0 = (h + 0 < HIDDEN) ? d * ax + b[h + 0] : 0.f;
        float o1 = (h + 1 < HIDDEN) ? d * ay + b[h + 1] : 0.f;
        float o2 = (h + 2 < HIDDEN) ? d * az + b[h + 2] : 0.f;
        float o3 = (h + 3 < HIDDEN) ? d * aw + b[h + 3] : 0.f;
        if (do_relu) {
            o0 = fmaxf(o0, 0.f); o1 = fmaxf(o1, 0.f);
            o2 = fmaxf(o2, 0.f); o3 = fmaxf(o3, 0.f);
        }
        B4[(size_t)n * 8 + s] = make_float4(o0, o1, o2, o3);
    }
}

__global__ void k_pool(const float* __restrict__ B, const int* __restrict__ gstart,
                       float* __restrict__ pooled, int G) {
    int g = blockIdx.x * 4 + (threadIdx.x >> 6);
    if (g >= G) return;
    int lane = threadIdx.x & 63;
    int h = lane & 31;
    int sub = lane >> 5;
    int beg = gstart[g], end = gstart[g + 1];
    float m = -INFINITY;
    if (h < HIDDEN) {
        for (int i = beg + sub; i < end; i += 2) m = fmaxf(m, B[(size_t)i * SP + h]);
    }
    float o = __shfl_down(m, 32);
    m = fmaxf(m, o);
    if (sub == 0 && h < HIDDEN) pooled[(size_t)g * HIDDEN + h] = (end > beg) ? m : 0.0f;
}

__global__ void k_final(const float* __restrict__ pooled, const float* __restrict__ Wlin,
                        const float* __restrict__ blin, float* __restrict__ out, int G) {
    int g = blockIdx.x * blockDim.x + threadIdx.x;
    if (g >= G) return;
    float a0 = blin[0], a1 = blin[1];
#pragma unroll
    for (int l = 0; l < 4; ++l) {
        for (int h = 0; h < HIDDEN; ++h) {
            float v = pooled[((size_t)l * G + g) * HIDDEN + h];
            int k = l * HIDDEN + h;
            a0 += v * Wlin[k * 2 + 0];
            a1 += v * Wlin[k * 2 + 1];
        }
    }
    out[g * 2 + 0] = a0;
    out[g * 2 + 1] = a1;
}

static inline size_t align256(size_t x) { return (x + 255) & ~(size_t)255; }

extern "C" void kernel_launch(void* const* d_in, const int* in_sizes, int n_in,
                              void* d_out, int out_size, void* d_ws, size_t ws_size,
                              hipStream_t stream) {
    const float* x     = (const float*)d_in[0];
    const int*   ei    = (const int*)d_in[1];
    const int*   batch = (const int*)d_in[2];
    const float* W0 = (const float*)d_in[4];
    const float* b0 = (const float*)d_in[5];
    const float* W1 = (const float*)d_in[6];
    const float* b1 = (const float*)d_in[7];
    const float* W2 = (const float*)d_in[8];
    const float* b2 = (const float*)d_in[9];
    const float* W3 = (const float*)d_in[10];
    const float* b3 = (const float*)d_in[11];
    const float* Wlin = (const float*)d_in[12];
    const float* blin = (const float*)d_in[13];

    const int N = in_sizes[0] / 128;
    const int E = in_sizes[1] / 2;
    const int G = out_size / 2;
    const int* row = ei;
    const int* col = ei + E;

    // bucket config: <=256 buckets of 2^shift nodes
    int shift = 9;
    while (((N + (1 << shift) - 1) >> shift) > 256) shift++;
    const int NB = (N + (1 << shift) - 1) >> shift;
    const int nblocksA = 256;
    const int chunk = (E + nblocksA - 1) / nblocksA;
    const int M = NB * nblocksA;

    char* ws = (char*)d_ws;
    size_t off = 0;
    unsigned* deg    = (unsigned*)(ws + off); off += align256((size_t)N * 4);
    unsigned* cnt    = (unsigned*)(ws + off); off += align256((size_t)N * 4);
    unsigned* rowptr = (unsigned*)(ws + off); off += align256(((size_t)N + 1) * 4);
    unsigned* bsum   = (unsigned*)(ws + off); off += align256(128 * 4);
    int*      gstart = (int*)(ws + off);      off += align256(((size_t)G + 1) * 4);
    float*    dis    = (float*)(ws + off);    off += align256((size_t)N * 4);
    unsigned* bh     = (unsigned*)(ws + off); off += align256((size_t)M * 4);
    int2*     pairs  = (int2*)(ws + off);     off += align256((size_t)E * 8);
    int*      src    = (int*)(ws + off);      off += align256((size_t)E * 4);
    float*    S      = (float*)(ws + off);    off += align256((size_t)N * SP * 4);
    float*    B      = (float*)(ws + off);    off += align256((size_t)N * SP * 4);
    float*    pooled = (float*)(ws + off);    off += align256((size_t)4 * G * HIDDEN * 4);

    const float* Wl[4] = {W0, W1, W2, W3};
    const float* bl[4] = {b0, b1, b2, b3};

    // ---- CSR build (once; reused by all 4 layers) ----
    hipMemsetAsync(deg, 0, (size_t)N * 4, stream);  // exact-size: ws is re-poisoned 0xAA
    k_hist<<<(E + 255) / 256, 256, 0, stream>>>(col, deg, E);
    k_dis<<<(N + 255) / 256, 256, 0, stream>>>(deg, dis, N);
    int nb = (N + 1023) / 1024;
    k_scan_block<<<nb, 1024, 0, stream>>>(deg, rowptr + 1, bsum, N);
    k_scan_bsums<<<1, 128, 0, stream>>>(bsum, nb);
    k_rowptr<<<nb, 1024, 0, stream>>>(bsum, rowptr, N);
    k_cnt_copy<<<(N + 255) / 256, 256, 0, stream>>>(rowptr, cnt, N);
    // bucketed edge sort
    k_bhist<<<nblocksA, 256, 0, stream>>>(col, bh, E, chunk, nblocksA, shift, NB);
    k_bscan<<<1, 1024, 0, stream>>>(bh, M);
    k_bscatter<<<nblocksA, 256, 0, stream>>>(row, col, bh, pairs, E, chunk, nblocksA, shift, NB);
    k_fscatter<<<NB, 256, 0, stream>>>(bh, pairs, cnt, src, E, nblocksA, NB);
    k_gstart<<<(N + 255) / 256, 256, 0, stream>>>(batch, gstart, N, G);

    // ---- 4 GCN layers ----
    int nblk8 = (N + 7) / 8;
    int nblk4 = (N + 3) / 4;
    for (int l = 0; l < 4; ++l) {
        if (l == 0) k_transform0<<<nblk8, 256, 0, stream>>>(x, W0, dis, S, N);
        else        k_transform_small<<<nblk8, 256, 0, stream>>>(B, Wl[l], dis, S, N);
        k_agg<<<nblk4, 256, 0, stream>>>(rowptr, src, (const float4*)S, dis, bl[l],
                                         (float4*)B, N, l < 3 ? 1 : 0);
        k_pool<<<(G + 3) / 4, 256, 0, stream>>>(B, gstart, pooled + (size_t)l * G * HIDDEN, G);
    }

    k_final<<<(G + 255) / 256, 256, 0, stream>>>(pooled, Wlin, blin, (float*)d_out, G);
}

// Round 11
// 591.529 us; speedup vs baseline: 1.1341x; 1.1341x over previous
//
#include <hip/hip_runtime.h>
#include <math.h>

#define HIDDEN 30
#define SP 32  // padded row stride (floats) -> 128B rows

// ---------------- degree / norm ----------------

__global__ void k_hist(const int* __restrict__ col, unsigned* __restrict__ deg, int E) {
    int e = blockIdx.x * blockDim.x + threadIdx.x;
    if (e < E) atomicAdd(&deg[col[e]], 1u);
}

__global__ void k_dis(const unsigned* __restrict__ deg, float* __restrict__ dis, int N) {
    int i = blockIdx.x * blockDim.x + threadIdx.x;
    if (i < N) dis[i] = rsqrtf((float)deg[i] + 1.0f);
}

// ---------------- hierarchical scan helpers ----------------

// inclusive scan in 1024-blocks; block totals to bsum
__global__ void k_scan_block(const unsigned* __restrict__ in, unsigned* __restrict__ inc,
                             unsigned* __restrict__ bsum, int N) {
    __shared__ unsigned s[1024];
    int i = blockIdx.x * 1024 + threadIdx.x;
    unsigned v = (i < N) ? in[i] : 0u;
    s[threadIdx.x] = v;
    __syncthreads();
    for (int off = 1; off < 1024; off <<= 1) {
        unsigned t = (threadIdx.x >= off) ? s[threadIdx.x - off] : 0u;
        __syncthreads();
        s[threadIdx.x] += t;
        __syncthreads();
    }
    if (i < N) inc[i] = s[threadIdx.x];
    if (threadIdx.x == 1023) bsum[blockIdx.x] = s[1023];
}

// inclusive scan of block sums (single block, nb <= 128)
__global__ void k_scan_bsums(unsigned* __restrict__ bsum, int nb) {
    __shared__ unsigned s[128];
    int i = threadIdx.x;
    s[i] = (i < nb) ? bsum[i] : 0u;
    __syncthreads();
    for (int off = 1; off < 128; off <<= 1) {
        unsigned t = (i >= off) ? s[i - off] : 0u;
        __syncthreads();
        s[i] += t;
        __syncthreads();
    }
    if (i < nb) bsum[i] = s[i];
}

// rowptr[i+1] += carry;  rowptr[0] = 0  (inclusive scan values already in rowptr[1..N])
__global__ void k_rowptr(const unsigned* __restrict__ bsum, unsigned* __restrict__ rowptr, int N) {
    int i = blockIdx.x * 1024 + threadIdx.x;
    if (i >= N) return;
    int blk = i >> 10;
    if (blk) rowptr[i + 1] += bsum[blk - 1];
    if (i == 0) rowptr[0] = 0u;
}

// exclusive from (per-block inclusive inc, scanned bsum): out[i] = global_incl[i-1], out[0]=0
__global__ void k_bexcl(const unsigned* __restrict__ inc, const unsigned* __restrict__ bsum,
                        unsigned* __restrict__ out, int M) {
    int i = blockIdx.x * 1024 + threadIdx.x;
    if (i >= M) return;
    unsigned v = 0u;
    if (i > 0) {
        int j = i - 1;
        int blk = j >> 10;
        v = inc[j] + (blk ? bsum[blk - 1] : 0u);
    }
    out[i] = v;
}

__global__ void k_cnt_copy(const unsigned* __restrict__ rowptr, unsigned* __restrict__ cnt, int N) {
    int i = blockIdx.x * blockDim.x + threadIdx.x;
    if (i < N) cnt[i] = rowptr[i];
}

// ---------------- bucketed edge sort (kills scatter write-amplification) ----------------

// per-block bucket histogram; blockhist[bucket*nblocks + block]
__global__ void k_bhist(const int* __restrict__ col, unsigned* __restrict__ blockhist,
                        int E, int chunk, int nblocks, int shift, int NB) {
    __shared__ unsigned h[256];
    for (int i = threadIdx.x; i < NB; i += 256) h[i] = 0;
    __syncthreads();
    int s = blockIdx.x * chunk, e = min(E, s + chunk);
    for (int j = s + threadIdx.x; j < e; j += 256) atomicAdd(&h[col[j] >> shift], 1u);
    __syncthreads();
    for (int i = threadIdx.x; i < NB; i += 256)
        blockhist[(size_t)i * nblocks + blockIdx.x] = h[i];
}

// write (row,col) pairs bucket-major; contiguous runs per (block,bucket)
__global__ void k_bscatter(const int* __restrict__ row, const int* __restrict__ col,
                           const unsigned* __restrict__ bh, int2* __restrict__ pairs,
                           int E, int chunk, int nblocks, int shift, int NB) {
    __shared__ unsigned base[256];
    __shared__ unsigned cnt[256];
    for (int i = threadIdx.x; i < NB; i += 256) {
        base[i] = bh[(size_t)i * nblocks + blockIdx.x];
        cnt[i] = 0;
    }
    __syncthreads();
    int s = blockIdx.x * chunk, e = min(E, s + chunk);
    for (int j = s + threadIdx.x; j < e; j += 256) {
        int c = col[j];
        int k = c >> shift;
        unsigned off = base[k] + atomicAdd(&cnt[k], 1u);
        pairs[off] = make_int2(row[j], c);
    }
}

// final positional scatter; one block per bucket -> writes stay in a ~32KB L2 window
__global__ void k_fscatter(const unsigned* __restrict__ bh, const int2* __restrict__ pairs,
                           unsigned* __restrict__ cnt, int* __restrict__ src,
                           int E, int nblocks, int NB) {
    int k = blockIdx.x;
    unsigned s = bh[(size_t)k * nblocks];
    unsigned e = (k + 1 < NB) ? bh[(size_t)(k + 1) * nblocks] : (unsigned)E;
    for (unsigned j = s + threadIdx.x; j < e; j += blockDim.x) {
        int2 p = pairs[j];
        unsigned q = atomicAdd(&cnt[p.y], 1u);
        src[q] = p.x;
    }
}

// per-graph node ranges from sorted batch
__global__ void k_gstart(const int* __restrict__ batch, int* __restrict__ gstart, int N, int G) {
    int i = blockIdx.x * blockDim.x + threadIdx.x;
    if (i >= N) return;
    int b = batch[i];
    if (i == 0) {
        for (int g = 0; g <= b; ++g) gstart[g] = 0;
    } else {
        int p = batch[i - 1];
        if (p != b) for (int g = p + 1; g <= b; ++g) gstart[g] = i;
    }
    if (i == N - 1) {
        for (int g = b + 1; g <= G; ++g) gstart[g] = N;
    }
}

// ---------------- per-layer kernels ----------------

__global__ void k_transform0(const float* __restrict__ x, const float* __restrict__ W,
                             const float* __restrict__ dis, float* __restrict__ S, int N) {
    __shared__ float Ws[128 * HIDDEN];
    __shared__ float Xs[8 * 128];
    for (int i = threadIdx.x; i < 128 * HIDDEN; i += 256) Ws[i] = W[i];
    int nb = blockIdx.x * 8;
    for (int i = threadIdx.x; i < 8 * 128; i += 256) {
        int nn = nb + (i >> 7);
        Xs[i] = (nn < N) ? x[(size_t)nn * 128 + (i & 127)] : 0.f;
    }
    __syncthreads();
    int nl = threadIdx.x >> 5, h = threadIdx.x & 31;
    int n = nb + nl;
    if (n >= N) return;
    float acc = 0.f;
    if (h < HIDDEN) {
        const float* xr = &Xs[nl * 128];
#pragma unroll 8
        for (int f = 0; f < 128; ++f) acc += xr[f] * Ws[f * HIDDEN + h];
        acc *= dis[n];
    }
    S[(size_t)n * SP + h] = (h < HIDDEN) ? acc : 0.f;
}

__global__ void k_transform_small(const float* __restrict__ in, const float* __restrict__ W,
                                  const float* __restrict__ dis, float* __restrict__ S, int N) {
    __shared__ float Ws[HIDDEN * HIDDEN];
    __shared__ float Bs[8 * SP];
    for (int i = threadIdx.x; i < HIDDEN * HIDDEN; i += 256) Ws[i] = W[i];
    int nb = blockIdx.x * 8;
    {
        int i = threadIdx.x;
        int nn = nb + (i >> 5);
        Bs[i] = (nn < N) ? in[(size_t)nn * SP + (i & 31)] : 0.f;
    }
    __syncthreads();
    int nl = threadIdx.x >> 5, h = threadIdx.x & 31;
    int n = nb + nl;
    if (n >= N) return;
    float acc = 0.f;
    if (h < HIDDEN) {
        const float* r = &Bs[nl * SP];
#pragma unroll
        for (int k = 0; k < HIDDEN; ++k) acc += r[k] * Ws[k * HIDDEN + h];
        acc *= dis[n];
    }
    S[(size_t)n * SP + h] = (h < HIDDEN) ? acc : 0.f;
}

// one wave per node: 8 lane-groups x float4 -> 8 neighbor rows (1KB) in flight/iter
__global__ void k_agg(const unsigned* __restrict__ rowptr, const int* __restrict__ src,
                      const float4* __restrict__ S4, const float* __restrict__ dis,
                      const float* __restrict__ b, float4* __restrict__ B4, int N, int do_relu) {
    int w = threadIdx.x >> 6;
    int lane = threadIdx.x & 63;
    int n = blockIdx.x * 4 + w;
    if (n >= N) return;
    int g = lane >> 3, s = lane & 7;
    float ax = 0.f, ay = 0.f, az = 0.f, aw = 0.f;
    if (g == 0) {  // self-loop term
        float4 v = S4[(size_t)n * 8 + s];
        ax = v.x; ay = v.y; az = v.z; aw = v.w;
    }
    unsigned beg = rowptr[n], end = rowptr[n + 1];
    for (unsigned j = beg + g; j < end; j += 8) {
        int r = src[j];
        float4 v = S4[(size_t)r * 8 + s];
        ax += v.x; ay += v.y; az += v.z; aw += v.w;
    }
    for (int off = 8; off < 64; off <<= 1) {
        ax += __shfl_xor(ax, off);
        ay += __shfl_xor(ay, off);
        az += __shfl_xor(az, off);
        aw += __shfl_xor(aw, off);
    }
    if (g == 0) {
        float d = dis[n];
        int h = s * 4;
        float o0 = (h + 0 < HIDDEN) ? d * ax + b[h + 0] : 0.f;
        float o1 = (h + 1 < HIDDEN) ? d * ay + b[h + 1] : 0.f;
        float o2 = (h + 2 < HIDDEN) ? d * az + b[h + 2] : 0.f;
        float o3 = (h + 3 < HIDDEN) ? d * aw + b[h + 3] : 0.f;
        if (do_relu) {
            o0 = fmaxf(o0, 0.f); o1 = fmaxf(o1, 0.f);
            o2 = fmaxf(o2, 0.f); o3 = fmaxf(o3, 0.f);
        }
        B4[(size_t)n * 8 + s] = make_float4(o0, o1, o2, o3);
    }
}

__global__ void k_pool(const float* __restrict__ B, const int* __restrict__ gstart,
                       float* __restrict__ pooled, int G) {
    int g = blockIdx.x * 4 + (threadIdx.x >> 6);
    if (g >= G) return;
    int lane = threadIdx.x & 63;
    int h = lane & 31;
    int sub = lane >> 5;
    int beg = gstart[g], end = gstart[g + 1];
    float m = -INFINITY;
    if (h < HIDDEN) {
        for (int i = beg + sub; i < end; i += 2) m = fmaxf(m, B[(size_t)i * SP + h]);
    }
    float o = __shfl_down(m, 32);
    m = fmaxf(m, o);
    if (sub == 0 && h < HIDDEN) pooled[(size_t)g * HIDDEN + h] = (end > beg) ? m : 0.0f;
}

__global__ void k_final(const float* __restrict__ pooled, const float* __restrict__ Wlin,
                        const float* __restrict__ blin, float* __restrict__ out, int G) {
    int g = blockIdx.x * blockDim.x + threadIdx.x;
    if (g >= G) return;
    float a0 = blin[0], a1 = blin[1];
#pragma unroll
    for (int l = 0; l < 4; ++l) {
        for (int h = 0; h < HIDDEN; ++h) {
            float v = pooled[((size_t)l * G + g) * HIDDEN + h];
            int k = l * HIDDEN + h;
            a0 += v * Wlin[k * 2 + 0];
            a1 += v * Wlin[k * 2 + 1];
        }
    }
    out[g * 2 + 0] = a0;
    out[g * 2 + 1] = a1;
}

static inline size_t align256(size_t x) { return (x + 255) & ~(size_t)255; }

extern "C" void kernel_launch(void* const* d_in, const int* in_sizes, int n_in,
                              void* d_out, int out_size, void* d_ws, size_t ws_size,
                              hipStream_t stream) {
    const float* x     = (const float*)d_in[0];
    const int*   ei    = (const int*)d_in[1];
    const int*   batch = (const int*)d_in[2];
    const float* W0 = (const float*)d_in[4];
    const float* b0 = (const float*)d_in[5];
    const float* W1 = (const float*)d_in[6];
    const float* b1 = (const float*)d_in[7];
    const float* W2 = (const float*)d_in[8];
    const float* b2 = (const float*)d_in[9];
    const float* W3 = (const float*)d_in[10];
    const float* b3 = (const float*)d_in[11];
    const float* Wlin = (const float*)d_in[12];
    const float* blin = (const float*)d_in[13];

    const int N = in_sizes[0] / 128;
    const int E = in_sizes[1] / 2;
    const int G = out_size / 2;
    const int* row = ei;
    const int* col = ei + E;

    // bucket config: <=256 buckets of 2^shift nodes
    int shift = 9;
    while (((N + (1 << shift) - 1) >> shift) > 256) shift++;
    const int NB = (N + (1 << shift) - 1) >> shift;
    const int nblocksA = 256;
    const int chunk = (E + nblocksA - 1) / nblocksA;
    const int M = NB * nblocksA;

    char* ws = (char*)d_ws;
    size_t off = 0;
    unsigned* deg    = (unsigned*)(ws + off); off += align256((size_t)N * 4);
    unsigned* cnt    = (unsigned*)(ws + off); off += align256((size_t)N * 4);
    unsigned* rowptr = (unsigned*)(ws + off); off += align256(((size_t)N + 1) * 4);
    unsigned* bsum   = (unsigned*)(ws + off); off += align256(128 * 4);
    unsigned* bsum2  = (unsigned*)(ws + off); off += align256(128 * 4);
    int*      gstart = (int*)(ws + off);      off += align256(((size_t)G + 1) * 4);
    float*    dis    = (float*)(ws + off);    off += align256((size_t)N * 4);
    unsigned* bh     = (unsigned*)(ws + off); off += align256((size_t)M * 4);
    unsigned* bhinc  = (unsigned*)(ws + off); off += align256((size_t)M * 4);
    int2*     pairs  = (int2*)(ws + off);     off += align256((size_t)E * 8);
    int*      src    = (int*)(ws + off);      off += align256((size_t)E * 4);
    float*    S      = (float*)(ws + off);    off += align256((size_t)N * SP * 4);
    float*    B      = (float*)(ws + off);    off += align256((size_t)N * SP * 4);
    float*    pooled = (float*)(ws + off);    off += align256((size_t)4 * G * HIDDEN * 4);

    const float* Wl[4] = {W0, W1, W2, W3};
    const float* bl[4] = {b0, b1, b2, b3};

    // ---- CSR build (once; reused by all 4 layers) ----
    hipMemsetAsync(deg, 0, (size_t)N * 4, stream);  // exact-size: ws is re-poisoned 0xAA
    k_hist<<<(E + 255) / 256, 256, 0, stream>>>(col, deg, E);
    k_dis<<<(N + 255) / 256, 256, 0, stream>>>(deg, dis, N);
    int nb = (N + 1023) / 1024;
    k_scan_block<<<nb, 1024, 0, stream>>>(deg, rowptr + 1, bsum, N);
    k_scan_bsums<<<1, 128, 0, stream>>>(bsum, nb);
    k_rowptr<<<nb, 1024, 0, stream>>>(bsum, rowptr, N);
    k_cnt_copy<<<(N + 255) / 256, 256, 0, stream>>>(rowptr, cnt, N);
    // bucketed edge sort (parallel exclusive scan of blockhist)
    k_bhist<<<nblocksA, 256, 0, stream>>>(col, bh, E, chunk, nblocksA, shift, NB);
    int nb2 = (M + 1023) / 1024;
    k_scan_block<<<nb2, 1024, 0, stream>>>(bh, bhinc, bsum2, M);
    k_scan_bsums<<<1, 128, 0, stream>>>(bsum2, nb2);
    k_bexcl<<<nb2, 1024, 0, stream>>>(bhinc, bsum2, bh, M);
    k_bscatter<<<nblocksA, 256, 0, stream>>>(row, col, bh, pairs, E, chunk, nblocksA, shift, NB);
    k_fscatter<<<NB, 256, 0, stream>>>(bh, pairs, cnt, src, E, nblocksA, NB);
    k_gstart<<<(N + 255) / 256, 256, 0, stream>>>(batch, gstart, N, G);

    // ---- 4 GCN layers ----
    int nblk8 = (N + 7) / 8;
    int nblk4 = (N + 3) / 4;
    for (int l = 0; l < 4; ++l) {
        if (l == 0) k_transform0<<<nblk8, 256, 0, stream>>>(x, W0, dis, S, N);
        else        k_transform_small<<<nblk8, 256, 0, stream>>>(B, Wl[l], dis, S, N);
        k_agg<<<nblk4, 256, 0, stream>>>(rowptr, src, (const float4*)S, dis, bl[l],
                                         (float4*)B, N, l < 3 ? 1 : 0);
        k_pool<<<(G + 3) / 4, 256, 0, stream>>>(B, gstart, pooled + (size_t)l * G * HIDDEN, G);
    }

    k_final<<<(G + 255) / 256, 256, 0, stream>>>(pooled, Wlin, blin, (float*)d_out, G);
}